// Round 3
// baseline (151923.206 us; speedup 1.0000x reference)
//
#include <hip/hip_runtime.h>

// All tensors are float32 per the reference.

// ---------------------------------------------------------------------------
// Stage A of layer k at timestep t:
//   zpre = x@Wxz.T + h@Whz.T + bz ; rpre likewise ; gx = x@Wxg.T + bg
//   publishes sigmoid(zpre), rh = sigmoid(rpre)*h, gx to ws.
// Grid: 256 blocks x 512 threads. Block = j-slice of 4; thread = (kq, b, jo).
// ---------------------------------------------------------------------------
__global__ __launch_bounds__(512) void gruA(
    const float* __restrict__ xin,   // base already offset to timestep t
    int xin_bstride, int Kx,
    const float* __restrict__ Wxz, const float* __restrict__ Wxr,
    const float* __restrict__ Wxg,
    const float* __restrict__ Whz, const float* __restrict__ Whr,
    const float* __restrict__ bz, const float* __restrict__ br,
    const float* __restrict__ bg,
    const float* __restrict__ hprev,    // this layer's h(t-1), f32 (32,1024)
    float* __restrict__ zsig, float* __restrict__ gxw,
    float* __restrict__ rh, int t)
{
    const int tt = threadIdx.x;
    const int kq = tt >> 7;          // 0..3  K-quarter
    const int b  = (tt >> 2) & 31;   // batch
    const int jo = tt & 3;
    const int j  = (blockIdx.x << 2) | jo;

    float az = 0.f, ar = 0.f, ag = 0.f;

    // x-side (K = Kx), split in quarters
    {
        const int q  = Kx >> 2;
        const int i0 = kq * q;
        const float4* xr  = (const float4*)(xin + (size_t)b * xin_bstride + i0);
        const float4* wzp = (const float4*)(Wxz + (size_t)j * Kx + i0);
        const float4* wrp = (const float4*)(Wxr + (size_t)j * Kx + i0);
        const float4* wgp = (const float4*)(Wxg + (size_t)j * Kx + i0);
        const int n4 = q >> 2;
        #pragma unroll 8
        for (int i = 0; i < n4; ++i) {
            float4 xv = xr[i];
            float4 a  = wzp[i];
            float4 c  = wrp[i];
            float4 d  = wgp[i];
            az += xv.x * a.x; az += xv.y * a.y; az += xv.z * a.z; az += xv.w * a.w;
            ar += xv.x * c.x; ar += xv.y * c.y; ar += xv.z * c.z; ar += xv.w * c.w;
            ag += xv.x * d.x; ag += xv.y * d.y; ag += xv.z * d.z; ag += xv.w * d.w;
        }
    }

    // h-side (K = 1024), skipped at t==0 (h == 0)
    if (t > 0) {
        const int k0 = kq << 8;      // 256 per quarter
        const float4* hr  = (const float4*)(hprev + (b << 10) + k0);
        const float4* wzp = (const float4*)(Whz + ((size_t)j << 10) + k0);
        const float4* wrp = (const float4*)(Whr + ((size_t)j << 10) + k0);
        #pragma unroll 8
        for (int i = 0; i < 64; ++i) {
            float4 hv = hr[i];
            float4 a  = wzp[i];
            float4 c  = wrp[i];
            az += hv.x * a.x; az += hv.y * a.y; az += hv.z * a.z; az += hv.w * a.w;
            ar += hv.x * c.x; ar += hv.y * c.y; ar += hv.z * c.z; ar += hv.w * c.w;
        }
    }

    __shared__ float red[3][512];
    red[0][tt] = az;
    red[1][tt] = ar;
    red[2][tt] = ag;
    __syncthreads();

    if (kq == 0) {   // tt in [0,128): one owner per (b, jo)
        float zp = red[0][tt] + red[0][tt + 128] + red[0][tt + 256] + red[0][tt + 384];
        float rp = red[1][tt] + red[1][tt + 128] + red[1][tt + 256] + red[1][tt + 384];
        float gp = red[2][tt] + red[2][tt + 128] + red[2][tt + 256] + red[2][tt + 384];
        zp += bz[j];
        rp += br[j];
        gp += bg[j];
        float zs = 1.f / (1.f + expf(-zp));
        float rs = 1.f / (1.f + expf(-rp));
        float hv = (t > 0) ? hprev[(b << 10) + j] : 0.f;
        const int idx = (b << 10) + j;
        zsig[idx] = zs;
        gxw[idx]  = gp;
        rh[idx]   = rs * hv;
    }
}

// ---------------------------------------------------------------------------
// Stage B: gpre = gx + (r*h) @ Whg.T ; h' = z*h + (1-z)*tanh(gpre)
// Updates this layer's h in place; at t==511 writes hidden_state out.
// Grid: 256 blocks x 256 threads. Thread = (kh, b, jo).
// ---------------------------------------------------------------------------
__global__ __launch_bounds__(256) void gruB(
    const float* __restrict__ Whg,
    const float* __restrict__ rh,
    const float* __restrict__ gxw, const float* __restrict__ zsig,
    float* __restrict__ h,           // this layer's h, updated in place
    float* __restrict__ outHid,      // d_out hidden base + layer*1024 (b-stride 3072)
    int t)
{
    const int tt = threadIdx.x;
    const int kh = tt >> 7;          // 0/1 K-half
    const int b  = (tt >> 2) & 31;
    const int jo = tt & 3;
    const int j  = (blockIdx.x << 2) | jo;

    float acc = 0.f;
    {
        const int k0 = kh << 9;      // 512 per half
        const float4* rr = (const float4*)(rh + (b << 10) + k0);
        const float4* wg = (const float4*)(Whg + ((size_t)j << 10) + k0);
        #pragma unroll 8
        for (int i = 0; i < 128; ++i) {
            float4 r4 = rr[i];
            float4 w4 = wg[i];
            acc += r4.x * w4.x; acc += r4.y * w4.y;
            acc += r4.z * w4.z; acc += r4.w * w4.w;
        }
    }

    __shared__ float red[256];
    red[tt] = acc;
    __syncthreads();

    if (kh == 0) {
        const int idx = (b << 10) + j;
        float gp = red[tt] + red[tt + 128] + gxw[idx];
        float g  = tanhf(gp);
        float hv = (t > 0) ? h[idx] : 0.f;
        float zs = zsig[idx];
        float hn = zs * hv + (1.f - zs) * g;
        h[idx] = hn;
        if (t == 511) outHid[b * 3072 + j] = hn;
    }
}

// ---------------------------------------------------------------------------
// Output head for one timestep: out[b,t,o] = h2[b,:] . Wout[o,:] + bout[o]
// Grid: 16 blocks x 256 threads, one thread per (b,o).
// ---------------------------------------------------------------------------
__global__ __launch_bounds__(256) void gruHeadT(
    const float* __restrict__ h2,     // h of layer 2, (32,1024)
    const float* __restrict__ Wout, const float* __restrict__ bout,
    float* __restrict__ out, int t)
{
    const int tid = blockIdx.x * 256 + threadIdx.x;   // 0..4095
    const int o = tid & 127;
    const int b = tid >> 7;

    const float4* hr = (const float4*)(h2 + (b << 10));
    const float4* wr = (const float4*)(Wout + ((size_t)o << 10));
    float acc = 0.f;
    #pragma unroll 8
    for (int i = 0; i < 256; ++i) {
        float4 h4 = hr[i];
        float4 w4 = wr[i];
        acc += h4.x * w4.x; acc += h4.y * w4.y;
        acc += h4.z * w4.z; acc += h4.w * w4.w;
    }
    acc += bout[o];
    out[((size_t)b << 16) | ((size_t)t << 7) | (size_t)o] = acc;
}

// ---------------------------------------------------------------------------
extern "C" void kernel_launch(void* const* d_in, const int* in_sizes, int n_in,
                              void* d_out, int out_size, void* d_ws, size_t ws_size,
                              hipStream_t stream)
{
    const float* x = (const float*)d_in[0];

    // Workspace (f32): h[3][32768] + zsig[32768] + gxw[32768] + rh[32768]
    //   total = 6*32768*4 = 786,432 bytes
    float* hst  = (float*)d_ws;          // 3 * 32768
    float* zsig = hst + 3 * 32768;
    float* gxw  = zsig + 32768;
    float* rhb  = gxw + 32768;

    float* outp   = (float*)d_out;       // (B,S,O) = 2,097,152
    float* outHid = outp + 2097152;      // (B,L,H) = 98,304

    // Per-layer weight pointers
    const float *Wxz[3], *Wxr[3], *Wxg[3], *Whz[3], *Whr[3], *Whg[3];
    const float *bz[3], *br[3], *bg[3];
    int Kx[3];
    Wxz[0] = (const float*)d_in[1]; Whz[0] = (const float*)d_in[2];
    bz[0]  = (const float*)d_in[3];
    Wxr[0] = (const float*)d_in[4]; Whr[0] = (const float*)d_in[5];
    br[0]  = (const float*)d_in[6];
    Wxg[0] = (const float*)d_in[7]; Whg[0] = (const float*)d_in[8];
    bg[0]  = (const float*)d_in[9];
    Kx[0] = 128;
    for (int k = 1; k < 3; ++k) {
        const size_t off = (size_t)(k - 1) * 1048576;   // H*H
        const size_t ob  = (size_t)(k - 1) * 1024;
        Wxz[k] = (const float*)d_in[10] + off; Whz[k] = (const float*)d_in[11] + off;
        bz[k]  = (const float*)d_in[12] + ob;
        Wxr[k] = (const float*)d_in[13] + off; Whr[k] = (const float*)d_in[14] + off;
        br[k]  = (const float*)d_in[15] + ob;
        Wxg[k] = (const float*)d_in[16] + off; Whg[k] = (const float*)d_in[17] + off;
        bg[k]  = (const float*)d_in[18] + ob;
        Kx[k] = 1024;
    }
    const float* Wout = (const float*)d_in[19];
    const float* bout = (const float*)d_in[20];

    for (int t = 0; t < 512; ++t) {
        for (int k = 0; k < 3; ++k) {
            const float* xin = (k == 0) ? (x + (size_t)t * 128)
                                        : (hst + (size_t)(k - 1) * 32768);
            const int bstride = (k == 0) ? 65536 : 1024;   // x is (B,S,I)
            gruA<<<256, 512, 0, stream>>>(xin, bstride, Kx[k],
                                          Wxz[k], Wxr[k], Wxg[k], Whz[k], Whr[k],
                                          bz[k], br[k], bg[k],
                                          hst + (size_t)k * 32768,
                                          zsig, gxw, rhb, t);
            gruB<<<256, 256, 0, stream>>>(Whg[k], rhb, gxw, zsig,
                                          hst + (size_t)k * 32768,
                                          outHid + (size_t)k * 1024, t);
        }
        gruHeadT<<<16, 256, 0, stream>>>(hst + 2 * 32768, Wout, bout, outp, t);
    }
}

// Round 4
// 67834.521 us; speedup vs baseline: 2.2396x; 2.2396x over previous
//
#include <hip/hip_runtime.h>

// Activations live in TRANSPOSED layout: T[k][b] at address k*32+b  (k<1024, b<32).
// Weights are torch-Linear rows W[j][k], read as wave-broadcast float4 (2-way
// divergence only: lanes = 32 b  x  2 k-subslices).

// ---------------------------------------------------------------------------
// Stage A of one layer at timestep t:
//   zpre = x@Wxz.T + h@Whz.T (+bz); rpre likewise; gx = x@Wxg.T (+bg)
//   outputs: zsigT = sigmoid(zpre), gxT = gx, rhT = sigmoid(rpre)*h(t-1)
// Grid 256 x 512. Block owns j in [4*blockIdx, 4*blockIdx+4).
// Wave w handles K-slices {w, w+8, ...} of the concat [x-K | h-K] space.
// ---------------------------------------------------------------------------
__global__ __launch_bounds__(512) void gruA(
    const float* __restrict__ x,      // raw x (B,S,I); used only when layer0=1
    const float* __restrict__ inT,    // layer>=1: input activations [Kx][32]
    const float* __restrict__ hT,     // this layer's h(t-1), [1024][32]
    const float* __restrict__ Wxz, const float* __restrict__ Wxr,
    const float* __restrict__ Wxg,
    const float* __restrict__ Whz, const float* __restrict__ Whr,
    const float* __restrict__ bz, const float* __restrict__ br,
    const float* __restrict__ bg,
    int Kx, int layer0, int t,
    float* __restrict__ zsigT, float* __restrict__ gxT,
    float* __restrict__ rhT)
{
    const int tid  = threadIdx.x;
    const int w    = tid >> 6;        // wave 0..7
    const int lane = tid & 63;
    const int b    = lane & 31;
    const int ks   = lane >> 5;       // 0/1 k-subslice
    const int jbase = blockIdx.x << 2;
    const int nslices = (Kx + 1024) >> 7;   // 9 (layer0) or 16

    float az[4] = {0.f,0.f,0.f,0.f};
    float ar[4] = {0.f,0.f,0.f,0.f};
    float ag[4] = {0.f,0.f,0.f,0.f};

    for (int s = w; s < nslices; s += 8) {
        const int k0 = s << 7;
        if (k0 < Kx) {
            // ---- x-region: 3 gates ----
            #pragma unroll 2
            for (int i = 0; i < 16; ++i) {
                const int kx = k0 + (i << 3) + (ks << 2);
                float o0, o1, o2, o3;
                if (layer0) {
                    const float4 xv = *(const float4*)(x + ((size_t)b << 16) + ((size_t)t << 7) + kx);
                    o0 = xv.x; o1 = xv.y; o2 = xv.z; o3 = xv.w;
                } else {
                    o0 = inT[(kx + 0) * 32 + b];
                    o1 = inT[(kx + 1) * 32 + b];
                    o2 = inT[(kx + 2) * 32 + b];
                    o3 = inT[(kx + 3) * 32 + b];
                }
                #pragma unroll
                for (int jj = 0; jj < 4; ++jj) {
                    const size_t row = (size_t)(jbase + jj) * Kx + kx;
                    const float4 wz = *(const float4*)(Wxz + row);
                    const float4 wr = *(const float4*)(Wxr + row);
                    const float4 wg = *(const float4*)(Wxg + row);
                    az[jj] += o0 * wz.x; az[jj] += o1 * wz.y;
                    az[jj] += o2 * wz.z; az[jj] += o3 * wz.w;
                    ar[jj] += o0 * wr.x; ar[jj] += o1 * wr.y;
                    ar[jj] += o2 * wr.z; ar[jj] += o3 * wr.w;
                    ag[jj] += o0 * wg.x; ag[jj] += o1 * wg.y;
                    ag[jj] += o2 * wg.z; ag[jj] += o3 * wg.w;
                }
            }
        } else if (t > 0) {
            // ---- h-region: z,r gates only (h(t-1)==0 at t==0) ----
            const int kh0 = k0 - Kx;
            #pragma unroll 2
            for (int i = 0; i < 16; ++i) {
                const int kh = kh0 + (i << 3) + (ks << 2);
                const float o0 = hT[(kh + 0) * 32 + b];
                const float o1 = hT[(kh + 1) * 32 + b];
                const float o2 = hT[(kh + 2) * 32 + b];
                const float o3 = hT[(kh + 3) * 32 + b];
                #pragma unroll
                for (int jj = 0; jj < 4; ++jj) {
                    const size_t row = ((size_t)(jbase + jj) << 10) + kh;
                    const float4 wz = *(const float4*)(Whz + row);
                    const float4 wr = *(const float4*)(Whr + row);
                    az[jj] += o0 * wz.x; az[jj] += o1 * wz.y;
                    az[jj] += o2 * wz.z; az[jj] += o3 * wz.w;
                    ar[jj] += o0 * wr.x; ar[jj] += o1 * wr.y;
                    ar[jj] += o2 * wr.z; ar[jj] += o3 * wr.w;
                }
            }
        }
    }

    // ks-pair reduction, then cross-wave combine in LDS
    #pragma unroll
    for (int jj = 0; jj < 4; ++jj) {
        az[jj] += __shfl_xor(az[jj], 32);
        ar[jj] += __shfl_xor(ar[jj], 32);
        ag[jj] += __shfl_xor(ag[jj], 32);
    }

    __shared__ float red[8 * 384 + 384];
    if (ks == 0) {
        #pragma unroll
        for (int jj = 0; jj < 4; ++jj) {
            red[w * 384 + (jj * 3 + 0) * 32 + b] = az[jj];
            red[w * 384 + (jj * 3 + 1) * 32 + b] = ar[jj];
            red[w * 384 + (jj * 3 + 2) * 32 + b] = ag[jj];
        }
    }
    __syncthreads();
    if (tid < 384) {
        float s = 0.f;
        #pragma unroll
        for (int ww = 0; ww < 8; ++ww) s += red[ww * 384 + tid];
        red[3072 + tid] = s;
    }
    __syncthreads();
    if (tid < 128) {
        const int jj = tid >> 5, bb = tid & 31;
        const int j = jbase + jj;
        const float zp = red[3072 + (jj * 3 + 0) * 32 + bb] + bz[j];
        const float rp = red[3072 + (jj * 3 + 1) * 32 + bb] + br[j];
        const float gp = red[3072 + (jj * 3 + 2) * 32 + bb] + bg[j];
        const float z = 1.f / (1.f + expf(-zp));
        const float r = 1.f / (1.f + expf(-rp));
        const float hp = (t > 0) ? hT[j * 32 + bb] : 0.f;
        zsigT[j * 32 + bb] = z;
        gxT[j * 32 + bb]   = gp;
        rhT[j * 32 + bb]   = r * hp;
    }
}

// ---------------------------------------------------------------------------
// Stage C: gpre = gxT + (r*h) @ Whg.T ; h' = z*h + (1-z)*tanh(gpre)
// Grid 256 x 512; block owns 4 j; wave w handles K-slice w (K=1024).
// ---------------------------------------------------------------------------
__global__ __launch_bounds__(512) void gruC(
    const float* __restrict__ Whg,
    const float* __restrict__ rhT, const float* __restrict__ gxT,
    const float* __restrict__ zsigT,
    float* __restrict__ hT,           // updated in place
    float* __restrict__ outHid,       // d_out + 2097152
    int layer, int t)
{
    const int tid  = threadIdx.x;
    const int w    = tid >> 6;
    const int lane = tid & 63;
    const int b    = lane & 31;
    const int ks   = lane >> 5;
    const int jbase = blockIdx.x << 2;

    float ac[4] = {0.f,0.f,0.f,0.f};
    const int k0 = w << 7;
    #pragma unroll 2
    for (int i = 0; i < 16; ++i) {
        const int k = k0 + (i << 3) + (ks << 2);
        const float o0 = rhT[(k + 0) * 32 + b];
        const float o1 = rhT[(k + 1) * 32 + b];
        const float o2 = rhT[(k + 2) * 32 + b];
        const float o3 = rhT[(k + 3) * 32 + b];
        #pragma unroll
        for (int jj = 0; jj < 4; ++jj) {
            const size_t row = ((size_t)(jbase + jj) << 10) + k;
            const float4 wg = *(const float4*)(Whg + row);
            ac[jj] += o0 * wg.x; ac[jj] += o1 * wg.y;
            ac[jj] += o2 * wg.z; ac[jj] += o3 * wg.w;
        }
    }
    #pragma unroll
    for (int jj = 0; jj < 4; ++jj) ac[jj] += __shfl_xor(ac[jj], 32);

    __shared__ float red[8 * 128 + 128];
    if (ks == 0) {
        #pragma unroll
        for (int jj = 0; jj < 4; ++jj)
            red[w * 128 + jj * 32 + b] = ac[jj];
    }
    __syncthreads();
    if (tid < 128) {
        float s = 0.f;
        #pragma unroll
        for (int ww = 0; ww < 8; ++ww) s += red[ww * 128 + tid];
        const int jj = tid >> 5, bb = tid & 31;
        const int j = jbase + jj;
        const float gpre = s + gxT[j * 32 + bb];
        const float g = tanhf(gpre);
        const float z = zsigT[j * 32 + bb];
        const float hp = (t > 0) ? hT[j * 32 + bb] : 0.f;
        const float hn = z * hp + (1.f - z) * g;
        hT[j * 32 + bb] = hn;
        if (t == 511) outHid[bb * 3072 + layer * 1024 + j] = hn;
    }
}

// ---------------------------------------------------------------------------
// Output head for one timestep: out[b,t,o] = h2 . Wout[o,:] + bout[o]
// Grid 32 x 512; block owns 4 o; wave w handles K-slice w (K=1024).
// ---------------------------------------------------------------------------
__global__ __launch_bounds__(512) void gruHead(
    const float* __restrict__ hT2,
    const float* __restrict__ Wout, const float* __restrict__ bout,
    float* __restrict__ out, int t)
{
    const int tid  = threadIdx.x;
    const int w    = tid >> 6;
    const int lane = tid & 63;
    const int b    = lane & 31;
    const int ks   = lane >> 5;
    const int obase = blockIdx.x << 2;

    float ac[4] = {0.f,0.f,0.f,0.f};
    const int k0 = w << 7;
    #pragma unroll 2
    for (int i = 0; i < 16; ++i) {
        const int k = k0 + (i << 3) + (ks << 2);
        const float o0 = hT2[(k + 0) * 32 + b];
        const float o1 = hT2[(k + 1) * 32 + b];
        const float o2 = hT2[(k + 2) * 32 + b];
        const float o3 = hT2[(k + 3) * 32 + b];
        #pragma unroll
        for (int oo = 0; oo < 4; ++oo) {
            const size_t row = ((size_t)(obase + oo) << 10) + k;
            const float4 wv = *(const float4*)(Wout + row);
            ac[oo] += o0 * wv.x; ac[oo] += o1 * wv.y;
            ac[oo] += o2 * wv.z; ac[oo] += o3 * wv.w;
        }
    }
    #pragma unroll
    for (int oo = 0; oo < 4; ++oo) ac[oo] += __shfl_xor(ac[oo], 32);

    __shared__ float red[8 * 128 + 128];
    if (ks == 0) {
        #pragma unroll
        for (int oo = 0; oo < 4; ++oo)
            red[w * 128 + oo * 32 + b] = ac[oo];
    }
    __syncthreads();
    if (tid < 128) {
        float s = 0.f;
        #pragma unroll
        for (int ww = 0; ww < 8; ++ww) s += red[ww * 128 + tid];
        const int oo = tid >> 5, bb = tid & 31;
        const int o = obase + oo;
        out[((size_t)bb << 16) + ((size_t)t << 7) + o] = s + bout[o];
    }
}

// ---------------------------------------------------------------------------
extern "C" void kernel_launch(void* const* d_in, const int* in_sizes, int n_in,
                              void* d_out, int out_size, void* d_ws, size_t ws_size,
                              hipStream_t stream)
{
    const float* x = (const float*)d_in[0];

    // Workspace (f32), all in transposed [k][b] layout — 786,432 bytes total.
    float* hT    = (float*)d_ws;          // [3][1024][32]
    float* zsigT = hT + 3 * 32768;        // [1024][32]
    float* gxT   = zsigT + 32768;
    float* rhT   = gxT + 32768;

    float* outp   = (float*)d_out;        // (B,S,O)
    float* outHid = outp + 2097152;       // (B,L,H)

    const float *Wxz[3], *Wxr[3], *Wxg[3], *Whz[3], *Whr[3], *Whg[3];
    const float *bz[3], *br[3], *bg[3];
    int Kx[3];
    Wxz[0] = (const float*)d_in[1]; Whz[0] = (const float*)d_in[2];
    bz[0]  = (const float*)d_in[3];
    Wxr[0] = (const float*)d_in[4]; Whr[0] = (const float*)d_in[5];
    br[0]  = (const float*)d_in[6];
    Wxg[0] = (const float*)d_in[7]; Whg[0] = (const float*)d_in[8];
    bg[0]  = (const float*)d_in[9];
    Kx[0] = 128;
    for (int k = 1; k < 3; ++k) {
        const size_t off = (size_t)(k - 1) * 1048576;
        const size_t ob  = (size_t)(k - 1) * 1024;
        Wxz[k] = (const float*)d_in[10] + off; Whz[k] = (const float*)d_in[11] + off;
        bz[k]  = (const float*)d_in[12] + ob;
        Wxr[k] = (const float*)d_in[13] + off; Whr[k] = (const float*)d_in[14] + off;
        br[k]  = (const float*)d_in[15] + ob;
        Wxg[k] = (const float*)d_in[16] + off; Whg[k] = (const float*)d_in[17] + off;
        bg[k]  = (const float*)d_in[18] + ob;
        Kx[k] = 1024;
    }
    const float* Wout = (const float*)d_in[19];
    const float* bout = (const float*)d_in[20];

    for (int t = 0; t < 512; ++t) {
        for (int k = 0; k < 3; ++k) {
            const float* inT = (k == 0) ? nullptr : (hT + (size_t)(k - 1) * 32768);
            gruA<<<256, 512, 0, stream>>>(x, inT,
                                          hT + (size_t)k * 32768,
                                          Wxz[k], Wxr[k], Wxg[k], Whz[k], Whr[k],
                                          bz[k], br[k], bg[k],
                                          Kx[k], (k == 0) ? 1 : 0, t,
                                          zsigT, gxT, rhT);
            gruC<<<256, 512, 0, stream>>>(Whg[k], rhT, gxT, zsigT,
                                          hT + (size_t)k * 32768,
                                          outHid, k, t);
        }
        gruHead<<<32, 512, 0, stream>>>(hT + 2 * 32768, Wout, bout, outp, t);
    }
}